// Round 2
// baseline (4108.437 us; speedup 1.0000x reference)
//
#include <hip/hip_runtime.h>
#include <cstdint>
#include <cstddef>

// Problem constants (fixed by setup_inputs)
#define HDIM 768
#define VOCAB 32000
#define NGATES 5
#define NJ 30
#define NB 16
#define NS 512
#define NBJ (NB*NJ)      // 480
#define G3 2304          // 3*H

typedef _Float16 f16;
typedef _Float16 f16x8 __attribute__((ext_vector_type(8)));
typedef float f32x4 __attribute__((ext_vector_type(4)));

// ---------------- fp32 -> fp16 cast (plain) ----------------
__global__ void k_cast(const float* __restrict__ src, f16* __restrict__ dst, int n) {
    for (int i = blockIdx.x*256 + threadIdx.x; i < n; i += gridDim.x*256)
        dst[i] = (f16)src[i];
}

// ---------------- fp32 -> fp16 hi/lo split cast ----------------
__global__ void k_cast_split(const float* __restrict__ src, f16* __restrict__ hi,
                             f16* __restrict__ lo, int n) {
    for (int i = blockIdx.x*256 + threadIdx.x; i < n; i += gridDim.x*256) {
        float v = src[i];
        f16 h = (f16)v;
        hi[i] = h;
        lo[i] = (f16)(v - (float)h);
    }
}

// ---------------- init w = sum of slot embeddings, h = hidden ----------------
__global__ void k_init_state(const float* __restrict__ E, const int* __restrict__ slot,
                             const float* __restrict__ hidden,
                             f16* __restrict__ w_hi, f16* __restrict__ w_lo,
                             float* __restrict__ h,
                             f16* __restrict__ h_hi, f16* __restrict__ h_lo) {
    int total = NBJ*HDIM;
    for (int i = blockIdx.x*256 + threadIdx.x; i < total; i += gridDim.x*256) {
        int hh = i % HDIM, row = i / HDIM;
        int b = row / NJ, j = row % NJ;
        float s = 0.f;
        #pragma unroll
        for (int l = 0; l < 4; ++l) s += E[(long)slot[j*4+l]*HDIM + hh];
        f16 sh = (f16)s;
        w_hi[i] = sh; w_lo[i] = (f16)(s - (float)sh);
        float hv = hidden[b*HDIM + hh];
        h[i] = hv;
        f16 hh16 = (f16)hv;
        h_hi[i] = hh16; h_lo[i] = (f16)(hv - (float)hh16);
    }
}

// ---------------- f16 GEMM, C[M][N] = A[M][K=768] * B[N][K=768]^T (BT layout) ----------------
// Split-fp16 mode (nspan=3): C = Ahi*Bhi^T + Ahi*Blo^T + Alo*Bhi^T  (fp32-grade accuracy).
// BM=128 BN=128 BK=64, 256 threads = 4 waves (2x2), wave tile 64x64.
// LDS frag-major: lds[c=k/8][rowcol 0..127][j 0..7] -> conflict-free ds_read_b128.
__launch_bounds__(256)
__global__ void k_gemm(const f16* __restrict__ Ah, const f16* __restrict__ Al,
                       const f16* __restrict__ Bh, const f16* __restrict__ Bl,
                       float* __restrict__ Cp,
                       int M, int N, long ldc, long coff, int nspan) {
    __shared__ f16 a_lds[8][128][8];   // 16 KB
    __shared__ f16 b_lds[8][128][8];   // 16 KB

    const int tid = threadIdx.x;
    const int m0 = blockIdx.x*128, n0 = blockIdx.y*128;
    const int w = tid >> 6, lane = tid & 63;
    const int wm = (w >> 1)*64, wn = (w & 1)*64;
    const int lr = lane & 15, lg = lane >> 4;
    const int srow = tid >> 1;        // 0..127
    const int p = tid & 1;            // which 32-k half this thread stages

    f32x4 acc[4][4] = {};

    for (int sp = 0; sp < nspan; ++sp) {
        const f16* Ap = (sp < 2) ? Ah : Al;
        const f16* Bp = (sp == 1) ? Bl : Bh;
        for (int kc = 0; kc < HDIM; kc += 64) {
            // ---- stage A (guard rows >= M with zeros) ----
            {
                long gr = m0 + srow;
                f16x8 v0 = {}, v1 = {}, v2 = {}, v3 = {};
                if (gr < M) {
                    const f16* src = Ap + gr*(long)HDIM + kc + p*32;
                    v0 = *(const f16x8*)(src);
                    v1 = *(const f16x8*)(src + 8);
                    v2 = *(const f16x8*)(src + 16);
                    v3 = *(const f16x8*)(src + 24);
                }
                *(f16x8*)&a_lds[p*4+0][srow][0] = v0;
                *(f16x8*)&a_lds[p*4+1][srow][0] = v1;
                *(f16x8*)&a_lds[p*4+2][srow][0] = v2;
                *(f16x8*)&a_lds[p*4+3][srow][0] = v3;
            }
            // ---- stage B (N always multiple of 128) ----
            {
                const f16* src = Bp + (long)(n0 + srow)*HDIM + kc + p*32;
                f16x8 v0 = *(const f16x8*)(src);
                f16x8 v1 = *(const f16x8*)(src + 8);
                f16x8 v2 = *(const f16x8*)(src + 16);
                f16x8 v3 = *(const f16x8*)(src + 24);
                *(f16x8*)&b_lds[p*4+0][srow][0] = v0;
                *(f16x8*)&b_lds[p*4+1][srow][0] = v1;
                *(f16x8*)&b_lds[p*4+2][srow][0] = v2;
                *(f16x8*)&b_lds[p*4+3][srow][0] = v3;
            }
            __syncthreads();
            #pragma unroll
            for (int kk = 0; kk < 2; ++kk) {
                const int c = kk*4 + lg;
                f16x8 af[4], bf[4];
                #pragma unroll
                for (int mi = 0; mi < 4; ++mi) af[mi] = *(const f16x8*)&a_lds[c][wm + mi*16 + lr][0];
                #pragma unroll
                for (int nf = 0; nf < 4; ++nf) bf[nf] = *(const f16x8*)&b_lds[c][wn + nf*16 + lr][0];
                #pragma unroll
                for (int mi = 0; mi < 4; ++mi)
                    #pragma unroll
                    for (int nf = 0; nf < 4; ++nf)
                        acc[mi][nf] = __builtin_amdgcn_mfma_f32_16x16x32_f16(af[mi], bf[nf], acc[mi][nf], 0, 0, 0);
            }
            __syncthreads();
        }
    }
    // epilogue: C/D layout col=lane&15, row=(lane>>4)*4+reg
    #pragma unroll
    for (int mi = 0; mi < 4; ++mi) {
        #pragma unroll
        for (int nf = 0; nf < 4; ++nf) {
            int col = n0 + wn + nf*16 + lr;
            int rowb = m0 + wm + mi*16 + lg*4;
            #pragma unroll
            for (int r = 0; r < 4; ++r) {
                int row = rowb + r;
                if (row < M) Cp[(long)row*ldc + coff + col] = acc[mi][nf][r];
            }
        }
    }
}

// ---------------- GRU elementwise ----------------
__global__ void k_gru_elem(const float* __restrict__ gi, const float* __restrict__ gh,
                           const float* __restrict__ bih, const float* __restrict__ bhh,
                           float* __restrict__ h, f16* __restrict__ h_hi, f16* __restrict__ h_lo) {
    int total = NBJ*HDIM;
    for (int i = blockIdx.x*256 + threadIdx.x; i < total; i += gridDim.x*256) {
        int c = i % HDIM; long row = i / HDIM;
        long base = row*G3;
        float r = gi[base + c]        + bih[c]        + gh[base + c]        + bhh[c];
        float z = gi[base + 768 + c]  + bih[768 + c]  + gh[base + 768 + c]  + bhh[768 + c];
        float hn = gh[base + 1536 + c] + bhh[1536 + c];
        float in_ = gi[base + 1536 + c] + bih[1536 + c];
        r = 1.f/(1.f + expf(-r));
        z = 1.f/(1.f + expf(-z));
        float n = tanhf(in_ + r*hn);
        float hv = (1.f - z)*n + z*h[i];
        h[i] = hv;
        f16 hh16 = (f16)hv;
        h_hi[i] = hh16; h_lo[i] = (f16)(hv - (float)hh16);
    }
}

// ---------------- attention scores: attn_e[row][s] = h[row] . enc[b][s][:] ----------------
__launch_bounds__(256)
__global__ void k_attn(const float* __restrict__ h, const float* __restrict__ enc,
                       float* __restrict__ attn_e) {
    __shared__ float h_lds[NJ][64];
    __shared__ float e_lds[64][65];   // +1 pad -> conflict-free
    const int b = blockIdx.x, st = blockIdx.y;
    const int s0 = st*64;
    const int tid = threadIdx.x;
    const int s = tid & 63, jg = tid >> 6;   // jg uniform per wave
    float acc[8] = {};
    for (int kc = 0; kc < HDIM; kc += 64) {
        for (int idx = tid; idx < NJ*64; idx += 256) {
            int j = idx >> 6, k = idx & 63;
            h_lds[j][k] = h[((long)(b*NJ + j))*HDIM + kc + k];
        }
        #pragma unroll
        for (int i = 0; i < 4; ++i) {
            int id = tid + i*256;
            int ss = id >> 4, kq = (id & 15)*4;
            float4 v = *(const float4*)&enc[((long)b*NS + s0 + ss)*HDIM + kc + kq];
            e_lds[ss][kq+0] = v.x; e_lds[ss][kq+1] = v.y;
            e_lds[ss][kq+2] = v.z; e_lds[ss][kq+3] = v.w;
        }
        __syncthreads();
        for (int k = 0; k < 64; ++k) {
            float e = e_lds[s][k];
            #pragma unroll
            for (int i = 0; i < 8; ++i) {
                int j = jg + i*4;
                if (j < NJ) acc[i] += h_lds[j][k]*e;
            }
        }
        __syncthreads();
    }
    #pragma unroll
    for (int i = 0; i < 8; ++i) {
        int j = jg + i*4;
        if (j < NJ) attn_e[((long)(b*NJ + j))*NS + s0 + s] = acc[i];
    }
}

// ---------------- masked softmax over S (in place) ----------------
__launch_bounds__(256)
__global__ void k_softmax_s(float* __restrict__ ae, const int* __restrict__ masks) {
    const int row = blockIdx.x, tid = threadIdx.x;
    const int b = row / NJ;
    __shared__ float red[256];
    float x0 = ae[(long)row*NS + tid];
    float x1 = ae[(long)row*NS + tid + 256];
    if (masks[b*NS + tid]       != 1) x0 = -1e9f;
    if (masks[b*NS + tid + 256] != 1) x1 = -1e9f;
    red[tid] = fmaxf(x0, x1); __syncthreads();
    for (int o = 128; o > 0; o >>= 1) { if (tid < o) red[tid] = fmaxf(red[tid], red[tid+o]); __syncthreads(); }
    float m = red[0]; __syncthreads();
    float e0 = expf(x0 - m), e1 = expf(x1 - m);
    red[tid] = e0 + e1; __syncthreads();
    for (int o = 128; o > 0; o >>= 1) { if (tid < o) red[tid] += red[tid+o]; __syncthreads(); }
    float inv = 1.f/red[0];
    ae[(long)row*NS + tid]       = e0*inv;
    ae[(long)row*NS + tid + 256] = e1*inv;
}

// ---------------- context[row][hh] = sum_s ah[row][s] * enc[b][s][hh] ----------------
__launch_bounds__(256)
__global__ void k_context(const float* __restrict__ ah, const float* __restrict__ enc,
                          float* __restrict__ ctx) {
    __shared__ float a_lds[NJ][64];
    const int b = blockIdx.x, ht = blockIdx.y;
    const int hh = ht*128 + (threadIdx.x & 127);
    const int jg = threadIdx.x >> 7;  // 0..1, uniform per wave
    float acc[15] = {};
    for (int sc = 0; sc < NS; sc += 64) {
        for (int idx = threadIdx.x; idx < NJ*64; idx += 256) {
            int j = idx >> 6, s = idx & 63;
            a_lds[j][s] = ah[((long)(b*NJ + j))*NS + sc + s];
        }
        __syncthreads();
        for (int s = 0; s < 64; ++s) {
            float e = enc[((long)b*NS + sc + s)*HDIM + hh];
            #pragma unroll
            for (int i = 0; i < 15; ++i) acc[i] += a_lds[jg + i*2][s]*e;
        }
        __syncthreads();
    }
    #pragma unroll
    for (int i = 0; i < 15; ++i) ctx[((long)(b*NJ + jg + i*2))*HDIM + hh] = acc[i];
}

// ---------------- p_gen (+ gates at t==0) ----------------
__launch_bounds__(64)
__global__ void k_pgen(const f16* __restrict__ w_hi, const f16* __restrict__ w_lo,
                       const float* __restrict__ h,
                       const float* __restrict__ ctx, const float* __restrict__ Wgen,
                       const float* __restrict__ bgen, const float* __restrict__ Wgate,
                       const float* __restrict__ bgate, float* __restrict__ pgen,
                       float* __restrict__ out_gates, int do_gate) {
    const int row = blockIdx.x, lane = threadIdx.x;
    float acc = 0.f;
    for (int x = lane; x < HDIM; x += 64) {
        float wv = (float)w_hi[(long)row*HDIM + x] + (float)w_lo[(long)row*HDIM + x];
        acc += wv                          * Wgen[x];
        acc += h[(long)row*HDIM + x]       * Wgen[768 + x];
        acc += ctx[(long)row*HDIM + x]     * Wgen[1536 + x];
    }
    for (int o = 32; o > 0; o >>= 1) acc += __shfl_down(acc, o);
    if (lane == 0) pgen[row] = 1.f/(1.f + expf(-(acc + bgen[0])));
    if (do_gate) {
        for (int g = 0; g < NGATES; ++g) {
            float a = 0.f;
            for (int x = lane; x < HDIM; x += 64) a += ctx[(long)row*HDIM + x]*Wgate[x*NGATES + g];
            for (int o = 32; o > 0; o >>= 1) a += __shfl_down(a, o);
            if (lane == 0) out_gates[row*NGATES + g] = a + bgate[g];
        }
    }
}

// ---------------- row max + sumexp over vocab logits ----------------
__launch_bounds__(256)
__global__ void k_rowstats(const float* __restrict__ pts, long ldrow, long coff,
                           float* __restrict__ rmax, float* __restrict__ rsum) {
    const int row = blockIdx.x, tid = threadIdx.x;
    const float* base = pts + (long)row*ldrow + coff;
    __shared__ float red[256];
    float m = -3.4e38f;
    for (int v = tid; v < VOCAB; v += 256) m = fmaxf(m, base[v]);
    red[tid] = m; __syncthreads();
    for (int o = 128; o > 0; o >>= 1) { if (tid < o) red[tid] = fmaxf(red[tid], red[tid+o]); __syncthreads(); }
    m = red[0]; __syncthreads();
    float s = 0.f;
    for (int v = tid; v < VOCAB; v += 256) s += expf(base[v] - m);
    red[tid] = s; __syncthreads();
    for (int o = 128; o > 0; o >>= 1) { if (tid < o) red[tid] += red[tid+o]; __syncthreads(); }
    if (tid == 0) { rmax[row] = m; rsum[row] = red[0]; }
}

// ---------------- p_gen * softmax in place + base argmax (first-index ties) ----------------
__launch_bounds__(256)
__global__ void k_final_a(float* __restrict__ pts, long ldrow, long coff,
                          const float* __restrict__ pgen, const float* __restrict__ rmax,
                          const float* __restrict__ rsum, unsigned long long* __restrict__ amax) {
    const int row = blockIdx.x, tid = threadIdx.x;
    float* base = pts + (long)row*ldrow + coff;
    const float m = rmax[row];
    const float scale = pgen[row] / rsum[row];
    float bv = -1.f; int bi = 0;
    for (int v = tid; v < VOCAB; v += 256) {
        float val = scale*expf(base[v] - m);
        base[v] = val;
        if (val > bv) { bv = val; bi = v; }   // strict ">" keeps smallest index per thread
    }
    __shared__ float rv[256]; __shared__ int ri[256];
    rv[tid] = bv; ri[tid] = bi; __syncthreads();
    for (int o = 128; o > 0; o >>= 1) {
        if (tid < o) {
            float v2 = rv[tid+o]; int i2 = ri[tid+o];
            if (v2 > rv[tid] || (v2 == rv[tid] && i2 < ri[tid])) { rv[tid] = v2; ri[tid] = i2; }
        }
        __syncthreads();
    }
    if (tid == 0)
        amax[row] = ((unsigned long long)__float_as_uint(rv[0]) << 32)
                  | (unsigned long long)(0xFFFFFFFFu - (unsigned)ri[0]);
}

// ---------------- pointer scatter + final argmax + gather next w (fp32 E, re-split) ----------------
__launch_bounds__(256)
__global__ void k_scatter(float* __restrict__ pts, long ldrow, long coff,
                          const int* __restrict__ ids, const float* __restrict__ ah,
                          const float* __restrict__ pgen, const unsigned long long* __restrict__ amax,
                          const float* __restrict__ E,
                          f16* __restrict__ w_hi, f16* __restrict__ w_lo) {
    const int row = blockIdx.x, tid = threadIdx.x;
    const int b = row / NJ;
    float* base = pts + (long)row*ldrow + coff;
    const float cp = 1.f - pgen[row];
    float bv = -1.f; int bi = 0x7FFFFFFF;
    for (int s = tid; s < NS; s += 256) {
        int id = ids[(long)b*NS + s];
        float add = cp * ah[(long)row*NS + s];
        float old = atomicAdd(base + id, add);
        float cand = old + add;   // temporally-last add on an address yields the true final value
        if (cand > bv || (cand == bv && id < bi)) { bv = cand; bi = id; }
    }
    __shared__ float rv[256]; __shared__ int ri[256];
    rv[tid] = bv; ri[tid] = bi; __syncthreads();
    for (int o = 128; o > 0; o >>= 1) {
        if (tid < o) {
            float v2 = rv[tid+o]; int i2 = ri[tid+o];
            if (v2 > rv[tid] || (v2 == rv[tid] && i2 < ri[tid])) { rv[tid] = v2; ri[tid] = i2; }
        }
        __syncthreads();
    }
    __shared__ int bidx;
    if (tid == 0) {
        unsigned long long pk = amax[row];
        float v0 = __uint_as_float((unsigned)(pk >> 32));
        int i0 = (int)(0xFFFFFFFFu - (unsigned)(pk & 0xFFFFFFFFu));
        if (rv[0] > v0 || (rv[0] == v0 && ri[0] < i0)) { v0 = rv[0]; i0 = ri[0]; }
        bidx = i0;
    }
    __syncthreads();
    const int idx = bidx;
    for (int x = tid; x < HDIM; x += 256) {
        float ev = E[(long)idx*HDIM + x];
        f16 eh = (f16)ev;
        w_hi[(long)row*HDIM + x] = eh;
        w_lo[(long)row*HDIM + x] = (f16)(ev - (float)eh);
    }
}

// ---------------- host ----------------
extern "C" void kernel_launch(void* const* d_in, const int* in_sizes, int n_in,
                              void* d_out, int out_size, void* d_ws, size_t ws_size,
                              hipStream_t stream) {
    const int*   input_ids = (const int*)  d_in[0];
    const float* enc       = (const float*)d_in[1];
    const float* hidden    = (const float*)d_in[2];
    const int*   masks     = (const int*)  d_in[3];
    const int*   slot      = (const int*)  d_in[4];
    // d_in[5] = max_len (device scalar) — derived from out_size instead
    const float* E     = (const float*)d_in[6];
    const float* Wih   = (const float*)d_in[7];
    const float* Whh   = (const float*)d_in[8];
    const float* bih   = (const float*)d_in[9];
    const float* bhh   = (const float*)d_in[10];
    const float* Wgen  = (const float*)d_in[11];
    const float* bgen  = (const float*)d_in[12];
    const float* Wgate = (const float*)d_in[13];
    const float* bgate = (const float*)d_in[14];

    const int ml = (out_size / NBJ - NGATES) / VOCAB;   // = 8
    float* out = (float*)d_out;
    float* gates_out = out + (long)NBJ*ml*VOCAB;

    // workspace carve (256B aligned)
    char* ws = (char*)d_ws;
    auto carve = [&](size_t bytes) { char* p = ws; ws += (bytes + 255) & ~(size_t)255; return p; };
    f16*   E16    = (f16*)  carve((size_t)VOCAB*HDIM*2);
    f16*   WihH   = (f16*)  carve((size_t)G3*HDIM*2);
    f16*   WihL   = (f16*)  carve((size_t)G3*HDIM*2);
    f16*   WhhH   = (f16*)  carve((size_t)G3*HDIM*2);
    f16*   WhhL   = (f16*)  carve((size_t)G3*HDIM*2);
    f16*   wH     = (f16*)  carve((size_t)NBJ*HDIM*2);
    f16*   wL     = (f16*)  carve((size_t)NBJ*HDIM*2);
    f16*   hH     = (f16*)  carve((size_t)NBJ*HDIM*2);
    f16*   hL     = (f16*)  carve((size_t)NBJ*HDIM*2);
    float* hbuf   = (float*)carve((size_t)NBJ*HDIM*4);
    float* gi     = (float*)carve((size_t)NBJ*G3*4);
    float* gh     = (float*)carve((size_t)NBJ*G3*4);
    float* ah     = (float*)carve((size_t)NBJ*NS*4);
    float* ctx    = (float*)carve((size_t)NBJ*HDIM*4);
    float* pgen   = (float*)carve((size_t)NBJ*4);
    float* rmax   = (float*)carve((size_t)NBJ*4);
    float* rsum   = (float*)carve((size_t)NBJ*4);
    unsigned long long* amax = (unsigned long long*)carve((size_t)NBJ*8);

    k_cast<<<8192, 256, 0, stream>>>(E, E16, VOCAB*HDIM);
    k_cast_split<<<2048, 256, 0, stream>>>(Wih, WihH, WihL, G3*HDIM);
    k_cast_split<<<2048, 256, 0, stream>>>(Whh, WhhH, WhhL, G3*HDIM);
    k_init_state<<<1440, 256, 0, stream>>>(E, slot, hidden, wH, wL, hbuf, hH, hL);

    const long ldrow = (long)ml*VOCAB;
    for (int t = 0; t < ml; ++t) {
        // GRU gates (split-fp16, fp32-grade): gi = w @ Wih^T, gh = h @ Whh^T
        k_gemm<<<dim3(4, 18), 256, 0, stream>>>(wH, wL, WihH, WihL, gi, NBJ, G3, (long)G3, 0, 3);
        k_gemm<<<dim3(4, 18), 256, 0, stream>>>(hH, hL, WhhH, WhhL, gh, NBJ, G3, (long)G3, 0, 3);
        k_gru_elem<<<1440, 256, 0, stream>>>(gi, gh, bih, bhh, hbuf, hH, hL);
        k_attn<<<dim3(NB, 8), 256, 0, stream>>>(hbuf, enc, ah);
        k_softmax_s<<<NBJ, 256, 0, stream>>>(ah, masks);
        k_context<<<dim3(NB, 6), 256, 0, stream>>>(ah, enc, ctx);
        k_pgen<<<NBJ, 64, 0, stream>>>(wH, wL, hbuf, ctx, Wgen, bgen, Wgate, bgate,
                                       pgen, gates_out, t == 0 ? 1 : 0);
        // vocab logits straight into d_out slice [row][t][:] (plain fp16 — error ~1e-7 in probs)
        k_gemm<<<dim3(4, 250), 256, 0, stream>>>(hH, nullptr, E16, nullptr, out,
                                                 NBJ, VOCAB, ldrow, (long)t*VOCAB, 1);
        k_rowstats<<<NBJ, 256, 0, stream>>>(out, ldrow, (long)t*VOCAB, rmax, rsum);
        k_final_a<<<NBJ, 256, 0, stream>>>(out, ldrow, (long)t*VOCAB, pgen, rmax, rsum, amax);
        k_scatter<<<NBJ, 256, 0, stream>>>(out, ldrow, (long)t*VOCAB, input_ids, ah, pgen,
                                           amax, E, wH, wL);
    }
}

// Round 3
// 2768.274 us; speedup vs baseline: 1.4841x; 1.4841x over previous
//
#include <hip/hip_runtime.h>
#include <cstdint>
#include <cstddef>

// Problem constants (fixed by setup_inputs)
#define HDIM 768
#define VOCAB 32000
#define NGATES 5
#define NJ 30
#define NB 16
#define NS 512
#define NBJ (NB*NJ)      // 480
#define G3 2304          // 3*H
#define PR 608           // padded state rows (max A-row read = 15*30+127 = 577)
#define NBV 250          // vocab n-blocks

typedef _Float16 f16;
typedef _Float16 f16x8 __attribute__((ext_vector_type(8)));
typedef float f32x4 __attribute__((ext_vector_type(4)));

#define GLOBAL_AS __attribute__((address_space(1)))
#define LDS_AS    __attribute__((address_space(3)))

// ---------------- fp32 -> fp16 cast (plain) ----------------
__global__ void k_cast(const float* __restrict__ src, f16* __restrict__ dst, int n) {
    for (int i = blockIdx.x*256 + threadIdx.x; i < n; i += gridDim.x*256)
        dst[i] = (f16)src[i];
}

// ---------------- fp32 -> fp16 hi/lo split cast ----------------
__global__ void k_cast_split(const float* __restrict__ src, f16* __restrict__ hi,
                             f16* __restrict__ lo, int n) {
    for (int i = blockIdx.x*256 + threadIdx.x; i < n; i += gridDim.x*256) {
        float v = src[i];
        f16 h = (f16)v;
        hi[i] = h;
        lo[i] = (f16)(v - (float)h);
    }
}

// ---------------- enc split + transposed split ----------------
// grid (16, 16, 24): b, s-tile(32), h-tile(32); 256 threads
__global__ void k_tsplit(const float* __restrict__ enc,
                         f16* __restrict__ encH, f16* __restrict__ encL,
                         f16* __restrict__ encTH, f16* __restrict__ encTL) {
    __shared__ float tile[32][33];
    const int b = blockIdx.x, s0 = blockIdx.y*32, h0 = blockIdx.z*32;
    const int t = threadIdx.x;
    const int hl = t & 31, sl = t >> 5;  // 8 s-rows per pass
    #pragma unroll
    for (int r = 0; r < 4; ++r) {
        int ss = sl + r*8;
        float v = enc[((long)b*NS + s0 + ss)*HDIM + h0 + hl];
        tile[ss][hl] = v;
        f16 h = (f16)v;
        long o = ((long)b*NS + s0 + ss)*HDIM + h0 + hl;
        encH[o] = h; encL[o] = (f16)(v - (float)h);
    }
    __syncthreads();
    #pragma unroll
    for (int r = 0; r < 4; ++r) {
        int hh = sl + r*8;           // now h index
        float v = tile[hl][hh];      // transposed read (stride-33: conflict-free)
        f16 h = (f16)v;
        long o = ((long)b*HDIM + h0 + hh)*NS + s0 + hl;
        encTH[o] = h; encTL[o] = (f16)(v - (float)h);
    }
}

// ---------------- init w = sum of slot embeddings, h = hidden ----------------
__global__ void k_init_state(const float* __restrict__ E, const int* __restrict__ slot,
                             const float* __restrict__ hidden,
                             f16* __restrict__ w_hi, f16* __restrict__ w_lo,
                             float* __restrict__ h,
                             f16* __restrict__ h_hi, f16* __restrict__ h_lo) {
    int total = NBJ*HDIM;
    for (int i = blockIdx.x*256 + threadIdx.x; i < total; i += gridDim.x*256) {
        int hh = i % HDIM, row = i / HDIM;
        int b = row / NJ, j = row % NJ;
        float s = 0.f;
        #pragma unroll
        for (int l = 0; l < 4; ++l) s += E[(long)slot[j*4+l]*HDIM + hh];
        f16 sh = (f16)s;
        w_hi[i] = sh; w_lo[i] = (f16)(s - (float)sh);
        float hv = hidden[b*HDIM + hh];
        h[i] = hv;
        f16 hh16 = (f16)hv;
        h_hi[i] = hh16; h_lo[i] = (f16)(hv - (float)hh16);
    }
}

// ---------------- unified split-f16 MFMA GEMM, C = A * B^T ----------------
// BM=BN=128, BK=64, 256 threads = 4 waves (2x2), wave tile 64x64.
// batch via blockIdx.z with element strides aBS/bBS/cBS.
// Staging via global_load_lds width-16 into frag-major LDS [c][row][8].
// A must be readable for rows m0..m0+127 (caller pads allocations); C guarded by M.
// If psum != nullptr: also emits per-block rowwise sum(exp(C)) into psum[by*512+row].
__launch_bounds__(256)
__global__ void k_gemm(const f16* __restrict__ Ah, const f16* __restrict__ Al,
                       const f16* __restrict__ Bh, const f16* __restrict__ Bl,
                       float* __restrict__ Cp, float* __restrict__ psum,
                       int M, long ldc, long coff, int kdim, int nspan,
                       long aBS, long bBS, long cBS) {
    __shared__ f16 a_lds[8][128][8];   // 16 KB
    __shared__ f16 b_lds[8][128][8];   // 16 KB
    __shared__ float sbuf[2][128];

    const int tid = threadIdx.x;
    const int z = blockIdx.z;
    const int m0 = blockIdx.x*128, n0 = blockIdx.y*128;
    const int w = tid >> 6, lane = tid & 63;
    const int wm = (w >> 1)*64, wn = (w & 1)*64;
    const int lr = lane & 15, lg = lane >> 4;

    f32x4 acc[4][4] = {};

    for (int sp = 0; sp < nspan; ++sp) {
        const f16* Ap = ((sp < 2) ? Ah : Al) + (long)z*aBS;
        const f16* Bp = ((sp == 1) ? Bl : Bh) + (long)z*bBS;
        for (int kc = 0; kc < kdim; kc += 64) {
            // stage A+B: per wave 4+4 global_load_lds (16B/lane), dest lane-linear
            #pragma unroll
            for (int i = 0; i < 4; ++i) {
                const int idx = w*4 + i;                  // 0..15
                const int c = idx >> 1;                    // k-octet
                const int rl = (idx & 1)*64 + lane;        // row 0..127
                const f16* ga = Ap + (long)(m0 + rl)*kdim + kc + c*8;
                const f16* gb = Bp + (long)(n0 + rl)*kdim + kc + c*8;
                __builtin_amdgcn_global_load_lds(
                    (const GLOBAL_AS unsigned int*)ga,
                    (LDS_AS unsigned int*)((char*)&a_lds[0][0][0] + idx*1024), 16, 0, 0);
                __builtin_amdgcn_global_load_lds(
                    (const GLOBAL_AS unsigned int*)gb,
                    (LDS_AS unsigned int*)((char*)&b_lds[0][0][0] + idx*1024), 16, 0, 0);
            }
            __syncthreads();
            #pragma unroll
            for (int kk = 0; kk < 2; ++kk) {
                const int c = kk*4 + lg;
                f16x8 af[4], bf[4];
                #pragma unroll
                for (int mi = 0; mi < 4; ++mi) af[mi] = *(const f16x8*)&a_lds[c][wm + mi*16 + lr][0];
                #pragma unroll
                for (int nf = 0; nf < 4; ++nf) bf[nf] = *(const f16x8*)&b_lds[c][wn + nf*16 + lr][0];
                #pragma unroll
                for (int mi = 0; mi < 4; ++mi)
                    #pragma unroll
                    for (int nf = 0; nf < 4; ++nf)
                        acc[mi][nf] = __builtin_amdgcn_mfma_f32_16x16x32_f16(af[mi], bf[nf], acc[mi][nf], 0, 0, 0);
            }
            __syncthreads();
        }
    }

    // C write: layout col=lane&15, row=(lane>>4)*4+reg
    float* Cb = Cp + (long)z*cBS + coff;
    #pragma unroll
    for (int mi = 0; mi < 4; ++mi) {
        #pragma unroll
        for (int nf = 0; nf < 4; ++nf) {
            int col = n0 + wn + nf*16 + lr;
            int rowb = m0 + wm + mi*16 + lg*4;
            #pragma unroll
            for (int r = 0; r < 4; ++r) {
                int row = rowb + r;
                if (row < M) Cb[(long)row*ldc + col] = acc[mi][nf][r];
            }
        }
    }

    // optional fused row-sumexp (vocab softmax denominator partials)
    if (psum != nullptr) {
        #pragma unroll
        for (int mi = 0; mi < 4; ++mi) {
            #pragma unroll
            for (int r = 0; r < 4; ++r) {
                float s = 0.f;
                #pragma unroll
                for (int nf = 0; nf < 4; ++nf) s += expf(acc[mi][nf][r]);
                s += __shfl_xor(s, 1); s += __shfl_xor(s, 2);
                s += __shfl_xor(s, 4); s += __shfl_xor(s, 8);
                if (lr == 0) sbuf[w & 1][wm + mi*16 + lg*4 + r] = s;
            }
        }
        __syncthreads();
        if (tid < 128)
            psum[(long)blockIdx.y*512 + m0 + tid] = sbuf[0][tid] + sbuf[1][tid];
    }
}

// ---------------- GRU elementwise ----------------
__global__ void k_gru_elem(const float* __restrict__ gi, const float* __restrict__ gh,
                           const float* __restrict__ bih, const float* __restrict__ bhh,
                           float* __restrict__ h, f16* __restrict__ h_hi, f16* __restrict__ h_lo) {
    int total = NBJ*HDIM;
    for (int i = blockIdx.x*256 + threadIdx.x; i < total; i += gridDim.x*256) {
        int c = i % HDIM; long row = i / HDIM;
        long base = row*G3;
        float r = gi[base + c]        + bih[c]        + gh[base + c]        + bhh[c];
        float z = gi[base + 768 + c]  + bih[768 + c]  + gh[base + 768 + c]  + bhh[768 + c];
        float hn = gh[base + 1536 + c] + bhh[1536 + c];
        float in_ = gi[base + 1536 + c] + bih[1536 + c];
        r = 1.f/(1.f + expf(-r));
        z = 1.f/(1.f + expf(-z));
        float n = tanhf(in_ + r*hn);
        float hv = (1.f - z)*n + z*h[i];
        h[i] = hv;
        f16 hh16 = (f16)hv;
        h_hi[i] = hh16; h_lo[i] = (f16)(hv - (float)hh16);
    }
}

// ---------------- masked softmax over S (in place) + split-f16 copy ----------------
__launch_bounds__(256)
__global__ void k_softmax_s(float* __restrict__ ae, const int* __restrict__ masks,
                            f16* __restrict__ ahH, f16* __restrict__ ahL) {
    const int row = blockIdx.x, tid = threadIdx.x;
    const int b = row / NJ;
    __shared__ float red[256];
    float x0 = ae[(long)row*NS + tid];
    float x1 = ae[(long)row*NS + tid + 256];
    if (masks[b*NS + tid]       != 1) x0 = -1e9f;
    if (masks[b*NS + tid + 256] != 1) x1 = -1e9f;
    red[tid] = fmaxf(x0, x1); __syncthreads();
    for (int o = 128; o > 0; o >>= 1) { if (tid < o) red[tid] = fmaxf(red[tid], red[tid+o]); __syncthreads(); }
    float m = red[0]; __syncthreads();
    float e0 = expf(x0 - m), e1 = expf(x1 - m);
    red[tid] = e0 + e1; __syncthreads();
    for (int o = 128; o > 0; o >>= 1) { if (tid < o) red[tid] += red[tid+o]; __syncthreads(); }
    float inv = 1.f/red[0];
    float p0 = e0*inv, p1 = e1*inv;
    ae[(long)row*NS + tid]       = p0;
    ae[(long)row*NS + tid + 256] = p1;
    f16 a0 = (f16)p0, a1 = (f16)p1;
    ahH[(long)row*NS + tid]       = a0; ahL[(long)row*NS + tid]       = (f16)(p0 - (float)a0);
    ahH[(long)row*NS + tid + 256] = a1; ahL[(long)row*NS + tid + 256] = (f16)(p1 - (float)a1);
}

// ---------------- p_gen (+ gates at t==0) ----------------
__launch_bounds__(64)
__global__ void k_pgen(const f16* __restrict__ w_hi, const f16* __restrict__ w_lo,
                       const float* __restrict__ h,
                       const float* __restrict__ ctx, const float* __restrict__ Wgen,
                       const float* __restrict__ bgen, const float* __restrict__ Wgate,
                       const float* __restrict__ bgate, float* __restrict__ pgen,
                       float* __restrict__ out_gates, int do_gate) {
    const int row = blockIdx.x, lane = threadIdx.x;
    float acc = 0.f;
    for (int x = lane; x < HDIM; x += 64) {
        float wv = (float)w_hi[(long)row*HDIM + x] + (float)w_lo[(long)row*HDIM + x];
        acc += wv                          * Wgen[x];
        acc += h[(long)row*HDIM + x]       * Wgen[768 + x];
        acc += ctx[(long)row*HDIM + x]     * Wgen[1536 + x];
    }
    for (int o = 32; o > 0; o >>= 1) acc += __shfl_down(acc, o);
    if (lane == 0) pgen[row] = 1.f/(1.f + expf(-(acc + bgen[0])));
    if (do_gate) {
        for (int g = 0; g < NGATES; ++g) {
            float a = 0.f;
            for (int x = lane; x < HDIM; x += 64) a += ctx[(long)row*HDIM + x]*Wgate[x*NGATES + g];
            for (int o = 32; o > 0; o >>= 1) a += __shfl_down(a, o);
            if (lane == 0) out_gates[row*NGATES + g] = a + bgate[g];
        }
    }
}

// ---------------- finalize: softmax-scale + argmax + pointer scatter + next-w gather ----------------
__launch_bounds__(256)
__global__ void k_finalize(float* __restrict__ pts, long ldrow, long coff,
                           const float* __restrict__ psum, const float* __restrict__ pgen,
                           const int* __restrict__ ids, const float* __restrict__ ah,
                           const float* __restrict__ E,
                           f16* __restrict__ w_hi, f16* __restrict__ w_lo) {
    const int row = blockIdx.x, tid = threadIdx.x;
    const int b = row / NJ;
    float* base = pts + (long)row*ldrow + coff;

    // 1) denominator = sum of per-block partials
    __shared__ float red[256];
    float s = 0.f;
    for (int nb = tid; nb < NBV; nb += 256) s += psum[(long)nb*512 + row];
    red[tid] = s; __syncthreads();
    for (int o = 128; o > 0; o >>= 1) { if (tid < o) red[tid] += red[tid+o]; __syncthreads(); }
    const float pg = pgen[row];
    const float scale = pg / red[0];

    // 2) p = pgen * exp(logit)/sum, in place; track argmax (first-index ties)
    float bv = -1.f; int bi = 0;
    for (int v = tid; v < VOCAB; v += 256) {
        float val = scale*expf(base[v]);
        base[v] = val;
        if (val > bv) { bv = val; bi = v; }
    }
    __shared__ float rv[256]; __shared__ int ri[256];
    rv[tid] = bv; ri[tid] = bi; __syncthreads();
    for (int o = 128; o > 0; o >>= 1) {
        if (tid < o) {
            float v2 = rv[tid+o]; int i2 = ri[tid+o];
            if (v2 > rv[tid] || (v2 == rv[tid] && i2 < ri[tid])) { rv[tid] = v2; ri[tid] = i2; }
        }
        __syncthreads();
    }
    float v0 = rv[0]; int i0 = ri[0];
    __syncthreads();   // all base[] writes drained before atomics

    // 3) pointer scatter; temporally-last add on an address yields its true final value
    const float cp = 1.f - pg;
    float sv = -1.f; int si = 0x7FFFFFFF;
    for (int ss = tid; ss < NS; ss += 256) {
        int id = ids[(long)b*NS + ss];
        float add = cp * ah[(long)row*NS + ss];
        float old = atomicAdd(base + id, add);
        float cand = old + add;
        if (cand > sv || (cand == sv && id < si)) { sv = cand; si = id; }
    }
    rv[tid] = sv; ri[tid] = si; __syncthreads();
    for (int o = 128; o > 0; o >>= 1) {
        if (tid < o) {
            float v2 = rv[tid+o]; int i2 = ri[tid+o];
            if (v2 > rv[tid] || (v2 == rv[tid] && i2 < ri[tid])) { rv[tid] = v2; ri[tid] = i2; }
        }
        __syncthreads();
    }
    __shared__ int bidx;
    if (tid == 0) {
        int ii = i0; float vv = v0;
        if (rv[0] > vv || (rv[0] == vv && ri[0] < ii)) { vv = rv[0]; ii = ri[0]; }
        bidx = ii;
    }
    __syncthreads();
    const int idx = bidx;
    for (int x = tid; x < HDIM; x += 256) {
        float ev = E[(long)idx*HDIM + x];
        f16 eh = (f16)ev;
        w_hi[(long)row*HDIM + x] = eh;
        w_lo[(long)row*HDIM + x] = (f16)(ev - (float)eh);
    }
}

// ---------------- host ----------------
extern "C" void kernel_launch(void* const* d_in, const int* in_sizes, int n_in,
                              void* d_out, int out_size, void* d_ws, size_t ws_size,
                              hipStream_t stream) {
    const int*   input_ids = (const int*)  d_in[0];
    const float* enc       = (const float*)d_in[1];
    const float* hidden    = (const float*)d_in[2];
    const int*   masks     = (const int*)  d_in[3];
    const int*   slot      = (const int*)  d_in[4];
    const float* E     = (const float*)d_in[6];
    const float* Wih   = (const float*)d_in[7];
    const float* Whh   = (const float*)d_in[8];
    const float* bih   = (const float*)d_in[9];
    const float* bhh   = (const float*)d_in[10];
    const float* Wgen  = (const float*)d_in[11];
    const float* bgen  = (const float*)d_in[12];
    const float* Wgate = (const float*)d_in[13];
    const float* bgate = (const float*)d_in[14];

    const int ml = (out_size / NBJ - NGATES) / VOCAB;   // = 8
    float* out = (float*)d_out;
    float* gates_out = out + (long)NBJ*ml*VOCAB;

    // workspace carve (256B aligned)
    char* ws = (char*)d_ws;
    auto carve = [&](size_t bytes) { char* p = ws; ws += (bytes + 255) & ~(size_t)255; return p; };
    f16*   E16   = (f16*)carve((size_t)VOCAB*HDIM*2);
    f16*   WH2   = (f16*)carve((size_t)2*G3*HDIM*2);   // WihH | WhhH (contiguous for batch-z)
    f16*   WL2   = (f16*)carve((size_t)2*G3*HDIM*2);
    f16*   SH    = (f16*)carve((size_t)2*PR*HDIM*2);   // wH | hH (padded rows)
    f16*   SL    = (f16*)carve((size_t)2*PR*HDIM*2);
    float* gigh  = (float*)carve((size_t)2*NBJ*G3*4);  // gi | gh
    f16*   encH  = (f16*)carve((size_t)NB*NS*HDIM*2);
    f16*   encL  = (f16*)carve((size_t)NB*NS*HDIM*2);
    f16*   encTH = (f16*)carve((size_t)NB*HDIM*NS*2);
    f16*   encTL = (f16*)carve((size_t)NB*HDIM*NS*2);
    float* hbuf  = (float*)carve((size_t)NBJ*HDIM*4);
    float* ae    = (float*)carve((size_t)NBJ*NS*4);
    f16*   ahH   = (f16*)carve((size_t)PR*NS*2);       // padded rows for ctx A-reads
    f16*   ahL   = (f16*)carve((size_t)PR*NS*2);
    float* ctx   = (float*)carve((size_t)NBJ*HDIM*4);
    float* pgen  = (float*)carve((size_t)NBJ*4);
    float* ps    = (float*)carve((size_t)NBV*512*4);

    f16* WihH = WH2;  f16* WihL = WL2;
    f16* wH = SH;     f16* wL = SL;
    f16* hH = SH + (size_t)PR*HDIM;
    f16* hL = SL + (size_t)PR*HDIM;
    float* gi = gigh; float* gh = gigh + (size_t)NBJ*G3;

    k_cast<<<8192, 256, 0, stream>>>(E, E16, VOCAB*HDIM);
    k_cast_split<<<2048, 256, 0, stream>>>(Wih, WihH, WihL, G3*HDIM);
    k_cast_split<<<2048, 256, 0, stream>>>(Whh, WH2 + (size_t)G3*HDIM, WL2 + (size_t)G3*HDIM, G3*HDIM);
    k_tsplit<<<dim3(NB, 16, 24), 256, 0, stream>>>(enc, encH, encL, encTH, encTL);
    k_init_state<<<1440, 256, 0, stream>>>(E, slot, hidden, wH, wL, hbuf, hH, hL);

    const long ldrow = (long)ml*VOCAB;
    for (int t = 0; t < ml; ++t) {
        // GRU gates, both in one launch: z=0: gi = w@Wih^T, z=1: gh = h@Whh^T (split-f16, 3 spans)
        k_gemm<<<dim3(4, 18, 2), 256, 0, stream>>>(wH, wL, WihH, WihL, gigh, nullptr,
            NBJ, (long)G3, 0, HDIM, 3, (long)PR*HDIM, (long)G3*HDIM, (long)NBJ*G3);
        k_gru_elem<<<1440, 256, 0, stream>>>(gi, gh, bih, bhh, hbuf, hH, hL);
        // attention scores: per batch z, ae[30 x 512] = h_b @ enc_b^T (split, 3 spans)
        k_gemm<<<dim3(1, 4, NB), 256, 0, stream>>>(hH, hL, encH, encL, ae, nullptr,
            NJ, (long)NS, 0, HDIM, 3, (long)NJ*HDIM, (long)NS*HDIM, (long)NJ*NS);
        k_softmax_s<<<NBJ, 256, 0, stream>>>(ae, masks, ahH, ahL);
        // context: per batch z, ctx[30 x 768] = ah_b @ encT_b^T (K = S = 512)
        k_gemm<<<dim3(1, 6, NB), 256, 0, stream>>>(ahH, ahL, encTH, encTL, ctx, nullptr,
            NJ, (long)HDIM, 0, NS, 3, (long)NJ*NS, (long)HDIM*NS, (long)NJ*HDIM);
        k_pgen<<<NBJ, 64, 0, stream>>>(wH, wL, hbuf, ctx, Wgen, bgen, Wgate, bgate,
                                       pgen, gates_out, t == 0 ? 1 : 0);
        // vocab logits into d_out slice + fused row-sumexp partials (no-max softmax)
        k_gemm<<<dim3(4, NBV, 1), 256, 0, stream>>>(hH, hL, E16, nullptr, out, ps,
            NBJ, ldrow, (long)t*VOCAB, HDIM, 1, 0, 0, 0);
        k_finalize<<<NBJ, 256, 0, stream>>>(out, ldrow, (long)t*VOCAB, ps, pgen,
                                            input_ids, ae, E, wH, wL);
    }
}